// Round 1
// baseline (350.461 us; speedup 1.0000x reference)
//
#include <hip/hip_runtime.h>
#include <hip/hip_bf16.h>
#include <stdint.h>

#define N_NODES 50000
#define N_EDGES 800000
#define NREL    8
#define NBASES  30
#define DIM     128
#define NSLOT   9                           // 8 relations + root
#define NCAT    (NSLOT*DIM)                 // 1152
#define SCAN_NB ((N_NODES + 255) / 256)     // 196 scan blocks
#define NB_C    196                         // coarse buckets (dst >> 8)
#define EPB_PLACE 2048
#define NBLK_PLACE ((N_EDGES + EPB_PLACE - 1) / EPB_PLACE)   // 391
#define GEMMH_TILES ((N_NODES + 63) / 64)   // 782
#define PREP_TOTAL  (NCAT * DIM + 2 * DIM * DIM)             // 180224
#define PREP_BLKS   ((PREP_TOTAL + 255) / 256)               // 704
#define CONV_BLKS   ((N_NODES * DIM / 4 + 255) / 256)        // 6250
#define HIST_BLKS   ((N_EDGES + 255) / 256)                  // 3125

typedef __attribute__((ext_vector_type(8))) short short8;
typedef __attribute__((ext_vector_type(4))) float floatx4;
typedef __hip_bfloat16  bf16;
typedef __hip_bfloat162 bf16x2;

__device__ inline ushort f2bu(float f) { bf16 b = __float2bfloat16(f); return *(ushort*)&b; }
__device__ inline float  bu2f(ushort u) { union { unsigned i; float f; } c; c.i = ((unsigned)u) << 16; return c.f; }

// ---------------- SETUP (merged): prep_weights | conv_x | hist, role by block range ----------------
// W2T layout: [o][r*128+k] = W[r][k][o] for r<8, = root[k][o] for r==8.  (B^T for h = s @ W2)
__global__ __launch_bounds__(256) void setup_kernel(const float* __restrict__ basis, const float* __restrict__ comp,
                                                    const float* __restrict__ root, const float* __restrict__ w_rel,
                                                    const float* __restrict__ w_root,
                                                    bf16* __restrict__ W2T, bf16* __restrict__ wrelT,
                                                    bf16* __restrict__ wrootT,
                                                    const float4* __restrict__ x4, ushort4* __restrict__ xb4,
                                                    const int* __restrict__ ei, int* __restrict__ deg) {
    int b = blockIdx.x;
    if (b < PREP_BLKS) {
        int idx = b * 256 + threadIdx.x;
        const int n_cat = NCAT * DIM;
        const int n_sq  = DIM * DIM;
        if (idx < n_cat) {
            int o = idx / NCAT;            // 0..127 (output dim) — consecutive threads: coalesced W2T write
            int rem = idx - o * NCAT;      // 0..1151 = r*128+k
            int r = rem >> 7, k = rem & 127;
            float v;
            if (r < NREL) {
                v = 0.f;
                for (int bb = 0; bb < NBASES; ++bb)
                    v += comp[r * NBASES + bb] * basis[(bb * DIM + k) * DIM + o];
            } else {
                v = root[k * DIM + o];
            }
            W2T[idx] = __float2bfloat16(v);
        } else if (idx < n_cat + n_sq) {
            int t = idx - n_cat; int k = t & 127, o = t >> 7;
            wrelT[o * DIM + k] = __float2bfloat16(w_rel[k * DIM + o]);
        } else if (idx < n_cat + 2 * n_sq) {
            int t = idx - n_cat - n_sq; int k = t & 127, o = t >> 7;
            wrootT[o * DIM + k] = __float2bfloat16(w_root[k * DIM + o]);
        }
    } else if (b < PREP_BLKS + CONV_BLKS) {
        int i = (b - PREP_BLKS) * 256 + threadIdx.x;
        int n4 = N_NODES * DIM / 4;
        if (i < n4) {
            float4 f = x4[i];
            ushort4 o;
            o.x = f2bu(f.x); o.y = f2bu(f.y); o.z = f2bu(f.z); o.w = f2bu(f.w);
            xb4[i] = o;
        }
    } else {
        int e = (b - PREP_BLKS - CONV_BLKS) * 256 + threadIdx.x;
        if (e < N_EDGES) atomicAdd(&deg[ei[N_EDGES + e]], 1);
    }
}

// ---------------- single-pass scan: decoupled lookback (196 blocks, all co-resident) ----------------
__global__ __launch_bounds__(256) void scan_one(const int* __restrict__ deg, int* __restrict__ segoff,
                                                unsigned long long* __restrict__ bstate, int n) {
    __shared__ int buf[256];
    int b = blockIdx.x, tid = threadIdx.x;
    int i = b * 256 + tid;
    int v = (i < n) ? deg[i] : 0;
    buf[tid] = v;
    __syncthreads();
#pragma unroll
    for (int o = 1; o < 256; o <<= 1) {
        int t = (tid >= o) ? buf[tid - o] : 0;
        __syncthreads();
        buf[tid] += t;
        __syncthreads();
    }
    int incl = buf[tid];
    int total = buf[255];
    if (tid == 0)
        __hip_atomic_store(&bstate[b], (1ULL << 32) | (unsigned)total,
                           __ATOMIC_RELEASE, __HIP_MEMORY_SCOPE_AGENT);
    int mysum = 0;
    for (int j = tid; j < b; j += 256) {
        unsigned long long s;
        do {
            s = __hip_atomic_load(&bstate[j], __ATOMIC_ACQUIRE, __HIP_MEMORY_SCOPE_AGENT);
        } while (!(s >> 32));
        mysum += (int)(s & 0xFFFFFFFFu);
    }
    __syncthreads();
    buf[tid] = mysum;
    __syncthreads();
#pragma unroll
    for (int o = 128; o > 0; o >>= 1) {
        if (tid < o) buf[tid] += buf[tid + o];
        __syncthreads();
    }
    int base = buf[0];
    if (i < n) segoff[i + 1] = base + incl;
    if (b == 0 && tid == 0) segoff[0] = 0;
}

// ---------------- sort pass A: coarse-bucket edge placement with run-reservation ----------------
__global__ __launch_bounds__(256) void place_kernel(const int* __restrict__ ei, const int* __restrict__ et,
                                                    const float* __restrict__ en, const int* __restrict__ segoff,
                                                    int* __restrict__ bcur, uint2* __restrict__ tmp) {
    __shared__ int lhist[NB_C];
    __shared__ int lbase[NB_C];
    __shared__ int lrank[NB_C];
    int tid = threadIdx.x;
    for (int i = tid; i < NB_C; i += 256) { lhist[i] = 0; lrank[i] = 0; }
    __syncthreads();
    int e0 = blockIdx.x * EPB_PLACE;
#pragma unroll
    for (int i = 0; i < EPB_PLACE / 256; ++i) {
        int e = e0 + i * 256 + tid;
        if (e < N_EDGES) atomicAdd(&lhist[ei[N_EDGES + e] >> 8], 1);
    }
    __syncthreads();
    for (int c = tid; c < NB_C; c += 256)
        if (lhist[c] > 0) lbase[c] = atomicAdd(&bcur[c], lhist[c]);
    __syncthreads();
#pragma unroll
    for (int i = 0; i < EPB_PLACE / 256; ++i) {
        int e = e0 + i * 256 + tid;
        if (e < N_EDGES) {
            int d = ei[N_EDGES + e];
            int c = d >> 8;
            int r = atomicAdd(&lrank[c], 1);
            int p = segoff[c << 8] + lbase[c] + r;
            tmp[p] = make_uint2((unsigned)ei[e] | ((unsigned)et[e] << 16) | ((unsigned)(d & 255) << 19),
                                __float_as_uint(en[e]));
        }
    }
}

// ---------------- sort pass B: finalize (dst, type)-sorted order within each coarse bucket ----------------
// Two-pass: (1) per-(node,typ) histogram, (2) per-node 8-bin exclusive prefix, (3) place.
// Type-sorting within node enables single-run register accumulation in gath1.
__global__ __launch_bounds__(256) void sortb_kernel(const uint2* __restrict__ tmp, const int* __restrict__ segoff,
                                                    uint2* __restrict__ rec) {
    __shared__ int hist2[256 * 8];        // (node_low, typ) counts -> running cursors
    int c = blockIdx.x;                   // 0..195
    int tid = threadIdx.x;
    for (int i = tid; i < 256 * 8; i += 256) hist2[i] = 0;
    __syncthreads();
    int base = segoff[c << 8];
    int nlimit = (c + 1) << 8; if (nlimit > N_NODES) nlimit = N_NODES;
    int end = segoff[nlimit];
    for (int i = base + tid; i < end; i += 256) {
        unsigned x = tmp[i].x;
        int dl = (x >> 19) & 255, ty = (x >> 16) & 7;
        atomicAdd(&hist2[dl * 8 + ty], 1);
    }
    __syncthreads();
    // thread tid owns node_low = tid: exclusive scan of its 8 bins, rebased to node start
    {
        int node = (c << 8) + tid;
        int run = (node < N_NODES) ? (segoff[node] - base) : 0;
#pragma unroll
        for (int t = 0; t < 8; ++t) {
            int cnt = hist2[tid * 8 + t];
            hist2[tid * 8 + t] = run;
            run += cnt;
        }
    }
    __syncthreads();
    for (int i = base + tid; i < end; i += 256) {
        uint2 r = tmp[i];
        int dl = (r.x >> 19) & 255, ty = (r.x >> 16) & 7;
        int p = base + atomicAdd(&hist2[dl * 8 + ty], 1);
        rec[p] = make_uint2(r.x & 0x7FFFFu, r.y);   // keep src(16) + type(3)
    }
}

__device__ inline void flush8(ushort* dst, const float* acc) {
    short8 o;
#pragma unroll
    for (int f = 0; f < 8; ++f) o[f] = (short)f2bu(acc[f]);
    *(short8*)dst = o;
}

// ---------------- layer-1 pre-aggregation: s[n, r*128+k] = sum norm*x[src][k]; slot 8 = x[n] ----------------
// quarter-wave (16 lanes/node, 8 dims/lane), ILP-4 loads; edges type-sorted per node so a single
// 8-register run accumulator suffices (flush on type change; zero-fill untouched slots via bitmask).
__global__ void gath1_kernel(const uint2* __restrict__ rec, const int* __restrict__ segoff,
                             const ushort* __restrict__ xb, ushort* __restrict__ s) {
    int quad = threadIdx.x >> 4;
    int node = blockIdx.x * 16 + quad;
    if (node >= N_NODES) return;
    int lane = threadIdx.x & 15;
    ushort* sp = s + (size_t)node * NCAT + lane * 8;
    int st = segoff[node], en = segoff[node + 1];
    float acc[8] = {0.f, 0.f, 0.f, 0.f, 0.f, 0.f, 0.f, 0.f};
    int cur = -1;
    unsigned mask = 0;
    for (int chunk = st; chunk < en; chunk += 4) {
        int m = en - chunk; if (m > 4) m = 4;
        uint2 rr[4]; short8 vv[4];
#pragma unroll
        for (int j = 0; j < 4; ++j) if (j < m) rr[j] = rec[chunk + j];
#pragma unroll
        for (int j = 0; j < 4; ++j) if (j < m)
            vv[j] = *(const short8*)(xb + (size_t)(rr[j].x & 0xFFFFu) * 128 + lane * 8);
#pragma unroll
        for (int j = 0; j < 4; ++j) if (j < m) {
            int ty = (int)(rr[j].x >> 16);
            if (ty != cur) {
                if (cur >= 0) flush8(sp + cur * 128, acc);
                cur = ty;
                mask |= 1u << ty;
#pragma unroll
                for (int f = 0; f < 8; ++f) acc[f] = 0.f;
            }
            float nrm = __uint_as_float(rr[j].y);
#pragma unroll
            for (int f = 0; f < 8; ++f) acc[f] += nrm * bu2f((ushort)vv[j][f]);
        }
    }
    if (cur >= 0) flush8(sp + cur * 128, acc);
    short8 z = {0, 0, 0, 0, 0, 0, 0, 0};
#pragma unroll
    for (int t = 0; t < 8; ++t)
        if (!(mask & (1u << t))) *(short8*)(sp + t * 128) = z;
    // root slot: copy x[node]
    *(short8*)(sp + 8 * 128) = *(const short8*)(xb + (size_t)node * 128 + lane * 8);
}

// ---------------- h = s @ W2 + bias1  ([50000,1152] x [1152,128] -> bf16 [50000,128]) ----------------
// 64-row x 128-col tile, K-loop of 9 chunks of 128; proven 136-stride LDS layout + 16x16x32 MFMA.
__global__ __launch_bounds__(256) void gemmh_kernel(const bf16* __restrict__ S, const bf16* __restrict__ B2T,
                                                    const float* __restrict__ bias1, bf16* __restrict__ H, int M) {
    __shared__ ushort As[64][136];
    __shared__ ushort Bs[128][136];
    const ushort* Su = (const ushort*)S;
    const ushort* Bu = (const ushort*)B2T;
    ushort* Hu = (ushort*)H;
    int tm = blockIdx.x * 64;
    int wave = threadIdx.x >> 6, lane = threadIdx.x & 63;
    int q = lane >> 4, mr = lane & 15;
    floatx4 zero = {0.f, 0.f, 0.f, 0.f};
    floatx4 acc[8] = {zero, zero, zero, zero, zero, zero, zero, zero};

    for (int ch = 0; ch < 9; ++ch) {
        if (ch) __syncthreads();
#pragma unroll
        for (int u = 0; u < 4; ++u) {
            int cc = threadIdx.x + u * 256;
            int row = cc >> 4, seg = cc & 15;
            int gr = tm + row;
            short8 av = {0, 0, 0, 0, 0, 0, 0, 0};
            if (gr < M) av = *(const short8*)(Su + (size_t)gr * NCAT + ch * 128 + seg * 8);
            *(short8*)(&As[row][seg * 8]) = av;
        }
#pragma unroll
        for (int u = 0; u < 8; ++u) {
            int cc = threadIdx.x + u * 256;
            int row = cc >> 4, seg = cc & 15;
            short8 bv = *(const short8*)(Bu + (size_t)row * NCAT + ch * 128 + seg * 8);
            *(short8*)(&Bs[row][seg * 8]) = bv;
        }
        __syncthreads();
#pragma unroll
        for (int kt = 0; kt < 4; ++kt) {
            short8 a = *(const short8*)(&As[wave * 16 + mr][q * 8 + kt * 32]);
#pragma unroll
            for (int nt = 0; nt < 8; ++nt) {
                short8 b = *(const short8*)(&Bs[nt * 16 + mr][q * 8 + kt * 32]);
                acc[nt] = __builtin_amdgcn_mfma_f32_16x16x32_bf16(a, b, acc[nt], 0, 0, 0);
            }
        }
    }
#pragma unroll
    for (int nt = 0; nt < 8; ++nt) {
        float bi = bias1[nt * 16 + mr];
#pragma unroll
        for (int r4 = 0; r4 < 4; ++r4) {
            int row = tm + wave * 16 + q * 4 + r4;
            if (row < M) Hu[(size_t)row * 128 + nt * 16 + mr] = f2bu(acc[nt][r4] + bi);
        }
    }
}

// ---------------- layer-2 segment sum: quarter-wave, ILP-4 ----------------
__global__ void seg2_kernel(const uint2* __restrict__ rec, const int* __restrict__ segoff,
                            const ushort* __restrict__ h, ushort* __restrict__ out2) {
    int quad = threadIdx.x >> 4;
    int node = blockIdx.x * 16 + quad;
    if (node >= N_NODES) return;
    int lane = threadIdx.x & 15;
    int st = segoff[node], en = segoff[node + 1];
    float acc[8] = {0.f, 0.f, 0.f, 0.f, 0.f, 0.f, 0.f, 0.f};
    for (int chunk = st; chunk < en; chunk += 4) {
        int m = en - chunk; if (m > 4) m = 4;
        uint2 rr[4]; short8 vv[4];
#pragma unroll
        for (int j = 0; j < 4; ++j) if (j < m) rr[j] = rec[chunk + j];
#pragma unroll
        for (int j = 0; j < 4; ++j) if (j < m)
            vv[j] = *(const short8*)(h + (size_t)(rr[j].x & 0xFFFFu) * 128 + lane * 8);
#pragma unroll
        for (int j = 0; j < 4; ++j) if (j < m)
#pragma unroll
            for (int f = 0; f < 8; ++f) acc[f] += bu2f((ushort)vv[j][f]);
    }
    short8 o;
#pragma unroll
    for (int f = 0; f < 8; ++f) o[f] = (short)f2bu(acc[f]);
    *(short8*)(out2 + (size_t)node * 128 + lane * 8) = o;
}

// ---------------- final GEMM: out[M,128](f32) = agg2@w_rel + h@w_root + b_rel ----------------
__global__ __launch_bounds__(256) void gemm2_kernel(const bf16* __restrict__ A1, const bf16* __restrict__ B1T,
                                                    const bf16* __restrict__ A2, const bf16* __restrict__ B2T,
                                                    const float* __restrict__ brel, float* __restrict__ out, int M) {
    __shared__ ushort As[64][136];
    __shared__ ushort Bs[64][136];
    int tm = blockIdx.x * 64, tn = blockIdx.y * 64;
    int wave = threadIdx.x >> 6, lane = threadIdx.x & 63;
    int q = lane >> 4, mr = lane & 15;
    floatx4 zero = {0.f, 0.f, 0.f, 0.f};
    floatx4 acc[4] = {zero, zero, zero, zero};

    for (int phase = 0; phase < 2; ++phase) {
        const ushort* Au = (const ushort*)(phase ? A2 : A1);
        const ushort* Bu = (const ushort*)(phase ? B2T : B1T);
        if (phase) __syncthreads();
        for (int c = threadIdx.x; c < 64 * 16; c += 256) {
            int row = c >> 4, seg = c & 15;
            int gr = tm + row;
            short8 av = {0, 0, 0, 0, 0, 0, 0, 0};
            if (gr < M) av = *(const short8*)(Au + (size_t)gr * 128 + seg * 8);
            *(short8*)(&As[row][seg * 8]) = av;
            short8 bv = *(const short8*)(Bu + (size_t)(tn + row) * 128 + seg * 8);
            *(short8*)(&Bs[row][seg * 8]) = bv;
        }
        __syncthreads();
#pragma unroll
        for (int kt = 0; kt < 4; ++kt) {
            short8 a = *(const short8*)(&As[wave * 16 + mr][q * 8 + kt * 32]);
#pragma unroll
            for (int nt = 0; nt < 4; ++nt) {
                short8 b = *(const short8*)(&Bs[nt * 16 + mr][q * 8 + kt * 32]);
                acc[nt] = __builtin_amdgcn_mfma_f32_16x16x32_bf16(a, b, acc[nt], 0, 0, 0);
            }
        }
    }
    __syncthreads();
    float* Csf = (float*)&As[0][0];
#pragma unroll
    for (int nt = 0; nt < 4; ++nt)
#pragma unroll
        for (int r4 = 0; r4 < 4; ++r4) {
            int row = wave * 16 + q * 4 + r4;
            int col = nt * 16 + mr;
            Csf[row * 68 + col] = acc[nt][r4] + brel[tn + col];
        }
    __syncthreads();
#pragma unroll
    for (int u = 0; u < 4; ++u) {
        int cc = threadIdx.x + u * 256;
        int row = cc >> 4, seg = cc & 15;
        int gr = tm + row;
        if (gr < M) {
            float4 v = *(const float4*)(&Csf[row * 68 + seg * 4]);
            *(float4*)(out + (size_t)gr * 128 + tn + seg * 4) = v;
        }
    }
}

extern "C" void kernel_launch(void* const* d_in, const int* in_sizes, int n_in,
                              void* d_out, int out_size, void* d_ws, size_t ws_size,
                              hipStream_t stream) {
    const float* x      = (const float*)d_in[0];
    const int*   ei     = (const int*)d_in[1];
    const int*   et     = (const int*)d_in[2];
    const float* en     = (const float*)d_in[3];
    const float* basis  = (const float*)d_in[4];
    const float* comp   = (const float*)d_in[5];
    const float* root   = (const float*)d_in[6];
    const float* bias1  = (const float*)d_in[7];
    const float* w_rel  = (const float*)d_in[8];
    const float* b_rel  = (const float*)d_in[9];
    const float* w_root = (const float*)d_in[10];
    float* out = (float*)d_out;

    char* ws = (char*)d_ws;
    size_t off = 0;
    auto alloc = [&](size_t bytes) { size_t o = off; off += (bytes + 255) & ~(size_t)255; return o; };

    size_t o_deg    = alloc((size_t)N_NODES * 4);        // zeroed
    size_t o_bcur   = alloc((size_t)NB_C * 4);           // zeroed
    size_t o_bstate = alloc((size_t)SCAN_NB * 8);        // zeroed (contiguous with deg)
    size_t o_segoff = alloc((size_t)(N_NODES + 1) * 4);
    size_t o_rec    = alloc((size_t)N_EDGES * 8);
    size_t o_tmp    = alloc((size_t)N_EDGES * 8);
    size_t o_w2t    = alloc((size_t)NCAT * DIM * 2);
    size_t o_wrel   = alloc((size_t)DIM * DIM * 2);
    size_t o_wroot  = alloc((size_t)DIM * DIM * 2);
    size_t o_xb     = alloc((size_t)N_NODES * DIM * 2);
    size_t o_s      = alloc((size_t)N_NODES * NCAT * 2); // 115.2 MB pre-aggregated s
    size_t o_hb     = alloc((size_t)N_NODES * DIM * 2);
    size_t o_agg2   = alloc((size_t)N_NODES * DIM * 2);

    int*   deg    = (int*)(ws + o_deg);
    int*   bcur   = (int*)(ws + o_bcur);
    unsigned long long* bstate = (unsigned long long*)(ws + o_bstate);
    int*   segoff = (int*)(ws + o_segoff);
    uint2* rec    = (uint2*)(ws + o_rec);
    uint2* tmp    = (uint2*)(ws + o_tmp);
    bf16*  w2t    = (bf16*)(ws + o_w2t);
    bf16*  wrelT  = (bf16*)(ws + o_wrel);
    bf16*  wrootT = (bf16*)(ws + o_wroot);
    bf16*  xb     = (bf16*)(ws + o_xb);
    bf16*  sbuf   = (bf16*)(ws + o_s);
    bf16*  hb     = (bf16*)(ws + o_hb);
    bf16*  agg2   = (bf16*)(ws + o_agg2);

    // zero deg + bcur + bstate (contiguous padded region)
    hipMemsetAsync(ws + o_deg, 0, o_segoff - o_deg, stream);

    // merged setup: weights prep (W2T layout) | x->bf16 | dst histogram
    setup_kernel<<<PREP_BLKS + CONV_BLKS + HIST_BLKS, 256, 0, stream>>>(
        basis, comp, root, w_rel, w_root, w2t, wrelT, wrootT,
        (const float4*)x, (ushort4*)xb, ei, deg);
    // single-pass decoupled-lookback scan
    scan_one<<<SCAN_NB, 256, 0, stream>>>(deg, segoff, bstate, N_NODES);
    // sort pass A: coarse placement
    place_kernel<<<NBLK_PLACE, 256, 0, stream>>>(ei, et, en, segoff, bcur, tmp);
    // sort pass B: (dst, type)-sorted within bucket
    sortb_kernel<<<NB_C, 256, 0, stream>>>(tmp, segoff, rec);
    // layer-1 pre-aggregation in input space -> s [N, 1152]
    gath1_kernel<<<(N_NODES + 15) / 16, 256, 0, stream>>>(rec, segoff, (const ushort*)xb, (ushort*)sbuf);
    // h = s @ W2 + bias1
    gemmh_kernel<<<GEMMH_TILES, 256, 0, stream>>>(sbuf, w2t, bias1, hb, N_NODES);
    // layer-2 aggregation
    seg2_kernel<<<(N_NODES + 15) / 16, 256, 0, stream>>>(rec, segoff, (const ushort*)hb, (ushort*)agg2);
    // out = agg2 @ w_rel + h @ w_root + b_rel
    {
        dim3 grid((N_NODES + 63) / 64, DIM / 64);
        gemm2_kernel<<<grid, 256, 0, stream>>>(agg2, wrelT, hb, wrootT, b_rel, out, N_NODES);
    }
}